// Round 19
// baseline (212.087 us; speedup 1.0000x reference)
//
#include <hip/hip_runtime.h>
#include <hip/hip_bf16.h>
#include <hip/hip_fp8.h>

// RGCN classifier, MI355X. Round 19: round-18 structure (mixed bf16/fp8 XW,
// 207.6us, absmax 1.25) + hardware fp8 cvt intrinsics (v_cvt_pk_f32_fp8 /
// v_cvt_pk_fp8_f32 — 1 VALU op per pair instead of a possible software path)
// and cnt-zeroing folded into prep (one fewer dispatch).
// ws layout (bytes):
//   XW      @ 0          : 150,994,944  (layer1: bf16 [node][1152]; layer2: fp8 low 75MB)
//   hb      @ 150994944  : 16,777,216   (h bf16)
//   h1b     @ 167772160  : 16,777,216
//   Wt1c    @ 184549376  : 294,912      (bf16 [tile*128+n][k])
//   Wt2c    @ 184844288  : 294,912
//   cnt     @ 185139200  : 262,144      (int per node; doubles as degree)
//   bins    @ 185401344  : 16,777,216   (uint [node][64]: u32-off src*576+et*64)
//   partial2@ 202178560  : 4,194,304    (bf16 [16384][128] pool partials)

#define N_NODES 65536
#define N_EDGES 786432
#define DIM 128
#define NT 9
#define XW_LD (NT * DIM) /* 1152 elems (bf16 layer) */
#define XW_LDB 1152      /* bytes per row (fp8 layer) */
#define N_GRAPHS 64
#define G_GEMM 4608
#define G_FUSED 10752  /* per XCD: 1344 = 576 gemm + 768 fill, interleaved 3:4 */

typedef unsigned int uint;
typedef unsigned short ushort;
typedef unsigned char uchar;
typedef __attribute__((ext_vector_type(8))) short short8;
typedef __attribute__((ext_vector_type(4))) float f32x4;
typedef __attribute__((ext_vector_type(2))) float f32x2;

__device__ inline ushort f2b(float f) {
  uint u = __float_as_uint(f);
  u += 0x7fff + ((u >> 16) & 1);   // RNE
  return (ushort)(u >> 16);
}
__device__ inline float b2f(ushort h) { return __uint_as_float(((uint)h) << 16); }
__device__ inline float blo(uint v) { return __uint_as_float(v << 16); }
__device__ inline float bhi(uint v) { return __uint_as_float(v & 0xffff0000u); }

// HW fp8 OCP e4m3 conversions (gfx950): 2 values per VALU instruction.
__device__ inline uchar f2fp8(float f) {
#if __has_builtin(__builtin_amdgcn_cvt_pk_fp8_f32)
  int p = __builtin_amdgcn_cvt_pk_fp8_f32(f, f, 0, false);
  return (uchar)(p & 0xff);
#else
  __hip_fp8_e4m3 q(f);
  return (uchar)q.__x;
#endif
}
__device__ inline f32x2 fp8x2_to_f32(int packed /* 2 fp8 in low 16 bits */) {
#if __has_builtin(__builtin_amdgcn_cvt_pk_f32_fp8)
  return __builtin_amdgcn_cvt_pk_f32_fp8(packed, false);
#else
  __hip_fp8_e4m3 a, b;
  a.__x = (uchar)(packed & 0xff);
  b.__x = (uchar)((packed >> 8) & 0xff);
  f32x2 r;
  r.x = (float)a;
  r.y = (float)b;
  return r;
#endif
}

__device__ inline void gl_lds16(const void* g, void* l) {
  __builtin_amdgcn_global_load_lds(
      (const __attribute__((address_space(1))) unsigned int*)g,
      (__attribute__((address_space(3))) unsigned int*)l, 16, 0, 0);
}

// ---------------- prep: h conversion (8192) + weights (18) + cnt zero (32) ---------
__global__ __launch_bounds__(256) void prep(const float* __restrict__ h,
                                            ushort* __restrict__ hb,
                                            const float* __restrict__ W1,
                                            const float* __restrict__ W1s,
                                            const float* __restrict__ W2,
                                            const float* __restrict__ W2s,
                                            ushort* __restrict__ Wt1,
                                            ushort* __restrict__ Wt2,
                                            int* __restrict__ cnt) {
  const int bid = blockIdx.x, tid = threadIdx.x;
  if (bid < 8192) {
    int i = bid * 256 + tid;
    float4 v = ((const float4*)h)[i];
    ushort4 o;
    o.x = f2b(v.x); o.y = f2b(v.y); o.z = f2b(v.z); o.w = f2b(v.w);
    ((ushort4*)hb)[i] = o;
  } else if (bid < 8210) {
    int b = bid - 8192;  // 0..17
    const float* S;
    ushort* D;
    int tile;
    if (b < 9) { D = Wt1; tile = b; S = (b < 8) ? (W1 + (size_t)b * 16384) : W1s; }
    else       { D = Wt2; tile = b - 9; S = (tile < 8) ? (W2 + (size_t)tile * 16384) : W2s; }
    for (int i = tid; i < 16384; i += 256) {
      int n = i >> 7, k = i & 127;
      D[((size_t)tile * 128 + n) * 128 + k] = f2b(S[k * 128 + n]);
    }
  } else {
    int i = (bid - 8210) * 256 + tid;      // 32 blocks x 256 x int4x2 = 65536 ints
    ((int4*)cnt)[i * 2] = (int4){0, 0, 0, 0};
    ((int4*)cnt)[i * 2 + 1] = (int4){0, 0, 0, 0};
  }
}

// ---------------- GEMM K-loop core (shared): acc = A_tile @ W_tile ----------------
__device__ __forceinline__ void gemm_core(const char* Ag, const char* Bg,
                                          char* lds, f32x4 (*acc)[4]) {
  const int tid = threadIdx.x, wv = tid >> 6, ln = tid & 63;
  const int wm = wv >> 1, wn = wv & 1, lr = ln & 15, kq = ln >> 4;
#pragma unroll
  for (int kt = 0; kt < 2; ++kt) {
    if (kt) __syncthreads();                  // prior phase's reads done
#pragma unroll
    for (int it = 0; it < 4; ++it) {
      int chunk = it * 4096 + wv * 1024;      // wave-uniform LDS base, 16KB total
      int p = chunk + ln * 16;                // linear lds byte pos
      int row = p >> 7, inb = p & 127;        // 128B rows
      int sw = inb ^ ((row & 7) << 4);        // pre-swizzled global source
      size_t gb = (size_t)row * 256 + (size_t)kt * 128 + sw;
      gl_lds16(Ag + gb, lds + chunk);
      gl_lds16(Bg + gb, lds + 16384 + chunk);
    }
    asm volatile("s_waitcnt vmcnt(0)" ::: "memory");
    __syncthreads();
#pragma unroll
    for (int k2 = 0; k2 < 2; ++k2) {
      const int kb = k2 * 64 + kq * 16;
      short8 a[4], b[4];
#pragma unroll
      for (int m = 0; m < 4; ++m) {
        int row = wm * 64 + m * 16 + lr;
        a[m] = *(const short8*)(lds + ((row * 128 + kb) ^ ((row & 7) << 4)));
      }
#pragma unroll
      for (int n = 0; n < 4; ++n) {
        int col = wn * 64 + n * 16 + lr;
        b[n] = *(const short8*)(lds + 16384 + ((col * 128 + kb) ^ ((col & 7) << 4)));
      }
#pragma unroll
      for (int m = 0; m < 4; ++m)
#pragma unroll
        for (int n = 0; n < 4; ++n)
          acc[m][n] = __builtin_amdgcn_mfma_f32_16x16x32_bf16(a[m], b[n], acc[m][n], 0, 0, 0);
    }
  }
}

// ---------------- layer-1 GEMM body: bf16 C, ldc=1152 elems ----------------
__device__ __forceinline__ void gemm_body_bf16(const ushort* __restrict__ A,
                                               const ushort* __restrict__ Bt,
                                               ushort* __restrict__ C,
                                               int tile, char* lds) {
  const int bm = tile / 9, bn = tile % 9;
  const int tid = threadIdx.x, wv = tid >> 6, ln = tid & 63;
  const int wm = wv >> 1, wn = wv & 1, lr = ln & 15, kq = ln >> 4;
  f32x4 acc[4][4];
#pragma unroll
  for (int m = 0; m < 4; ++m)
#pragma unroll
    for (int n = 0; n < 4; ++n) acc[m][n] = (f32x4){0.f, 0.f, 0.f, 0.f};
  gemm_core((const char*)(A + (size_t)bm * 128 * 128),
            (const char*)(Bt + (size_t)bn * 128 * 128), lds, acc);

  __syncthreads();  // stage-buffer reads complete before reuse
#pragma unroll
  for (int m = 0; m < 4; ++m) {
    int rb0 = wm * 64 + m * 16 + kq * 4;
#pragma unroll
    for (int n = 0; n < 4; ++n) {
      int col = wn * 64 + n * 16 + lr;
#pragma unroll
      for (int e = 0; e < 4; ++e) {
        int row = rb0 + e;
        int off = (row * 256 + col * 2) ^ ((row & 7) << 4);
        *(ushort*)(lds + off) = f2b(acc[m][n][e]);
      }
    }
  }
  __syncthreads();
  char* Cg = (char*)C + (size_t)(bm * 128) * XW_LD * 2 + (size_t)bn * 256;
#pragma unroll
  for (int it = 0; it < 8; ++it) {
    int p = it * 4096 + tid * 16;
    int row = p >> 8, inb = p & 255;
    short8 v = *(const short8*)(lds + row * 256 + (inb ^ ((row & 7) << 4)));
    *(short8*)(Cg + (size_t)row * XW_LD * 2 + inb) = v;
  }
}

// ---------------- layer-2 GEMM: fp8 C, row stride 1152 bytes ----------------
__global__ __launch_bounds__(256, 4) void gemm_bk64_fp8(const ushort* __restrict__ A,
                                                        const ushort* __restrict__ Bt,
                                                        uchar* __restrict__ C) {
  __shared__ char lds[32768];
  const int tile = (blockIdx.x & 7) * 576 + (blockIdx.x >> 3);
  const int bm = tile / 9, bn = tile % 9;
  const int tid = threadIdx.x, wv = tid >> 6, ln = tid & 63;
  const int wm = wv >> 1, wn = wv & 1, lr = ln & 15, kq = ln >> 4;
  f32x4 acc[4][4];
#pragma unroll
  for (int m = 0; m < 4; ++m)
#pragma unroll
    for (int n = 0; n < 4; ++n) acc[m][n] = (f32x4){0.f, 0.f, 0.f, 0.f};
  gemm_core((const char*)(A + (size_t)bm * 128 * 128),
            (const char*)(Bt + (size_t)bn * 128 * 128), lds, acc);

  __syncthreads();
#pragma unroll
  for (int m = 0; m < 4; ++m) {
    int rb0 = wm * 64 + m * 16 + kq * 4;
#pragma unroll
    for (int n = 0; n < 4; ++n) {
      int col = wn * 64 + n * 16 + lr;
#pragma unroll
      for (int e = 0; e < 4; ++e) {
        int row = rb0 + e;
        int off = (row * 128 + col) ^ ((row & 7) << 4);
        *(uchar*)(lds + off) = f2fp8(acc[m][n][e]);
      }
    }
  }
  __syncthreads();
  uchar* Cg = C + (size_t)(bm * 128) * XW_LDB + (size_t)bn * 128;
#pragma unroll
  for (int it = 0; it < 4; ++it) {
    int p = it * 4096 + tid * 16;
    int row = p >> 7, inb = p & 127;
    short8 v = *(const short8*)(lds + row * 128 + (inb ^ ((row & 7) << 4)));
    *(short8*)(Cg + (size_t)row * XW_LDB + inb) = v;
  }
}

// layer-1 GEMM + interleaved edge binning (round-12 packaging, best measured).
// Per XCD (bid&7) the sequence s=bid>>3 splits 3 gemm : 4 fill per group of 7.
// fill: slice=xcd owns dst [xcd*8192,(xcd+1)*8192); rec = src*576 + et*64.
__global__ __launch_bounds__(256, 4) void gemm1_fill(const ushort* __restrict__ A,
                                                     const ushort* __restrict__ Bt,
                                                     ushort* __restrict__ C,
                                                     const int* __restrict__ src,
                                                     const int* __restrict__ dst,
                                                     const int* __restrict__ et,
                                                     int* __restrict__ cnt,
                                                     uint* __restrict__ bins) {
  __shared__ char lds[32768];
  const int bid = blockIdx.x;            // 10752
  const int xcd = bid & 7, s = bid >> 3; // s in [0,1344)
  const int q = s / 7, r = s % 7;
  if (r < 3) {
    gemm_body_bf16(A, Bt, C, xcd * 576 + q * 3 + r, lds);
    return;
  }
  const int f = q * 4 + (r - 3);         // 0..767
  const int e0 = f * 1024 + threadIdx.x * 4;
  int4 d4 = *(const int4*)(dst + e0);
  int4 s4 = *(const int4*)(src + e0);
  int4 t4 = *(const int4*)(et + e0);
  uint r0 = (uint)s4.x * 576u + (uint)t4.x * 64u;
  uint r1 = (uint)s4.y * 576u + (uint)t4.y * 64u;
  uint r2 = (uint)s4.z * 576u + (uint)t4.z * 64u;
  uint r3 = (uint)s4.w * 576u + (uint)t4.w * 64u;
  if ((d4.x >> 13) == xcd) {
    int rk = atomicAdd(&cnt[d4.x], 1);
    if (rk < 64) bins[((size_t)d4.x << 6) + rk] = r0;
  }
  if ((d4.y >> 13) == xcd) {
    int rk = atomicAdd(&cnt[d4.y], 1);
    if (rk < 64) bins[((size_t)d4.y << 6) + rk] = r1;
  }
  if ((d4.z >> 13) == xcd) {
    int rk = atomicAdd(&cnt[d4.z], 1);
    if (rk < 64) bins[((size_t)d4.z << 6) + rk] = r2;
  }
  if ((d4.w >> 13) == xcd) {
    int rk = atomicAdd(&cnt[d4.w], 1);
    if (rk < 64) bins[((size_t)d4.w << 6) + rk] = r3;
  }
}

// ---------------- layer-1 gather (bf16 XW): h1 = relu(sum + self + b1) --------------
__global__ __launch_bounds__(256) void gather_bf16(const uint* __restrict__ XWu,
                                                   const uint* __restrict__ bins,
                                                   const int* __restrict__ cnt,
                                                   const float* __restrict__ bias,
                                                   uint* __restrict__ hout) {
  int node = (blockIdx.x * 256 + threadIdx.x) >> 6;
  int ln = threadIdx.x & 63;
  int ne = __builtin_amdgcn_readfirstlane(cnt[node]);
  if (ne > 64) ne = 64;
  uint sv = XWu[(size_t)node * 576 + 512 + ln];
  float2 bv = ((const float2*)bias)[ln];
  uint mv = bins[((size_t)node << 6) + ln];
  float2 acc = {0.f, 0.f};

#define EDGE(ii)                                                              \
  do {                                                                        \
    uint off = (uint)__builtin_amdgcn_readlane((int)mv, (ii));                \
    uint v_ = XWu[off + ln];                                                  \
    acc.x += blo(v_); acc.y += bhi(v_);                                       \
  } while (0)
  int i = 0;
  for (; i + 8 <= ne; i += 8) {
    EDGE(i + 0); EDGE(i + 1); EDGE(i + 2); EDGE(i + 3);
    EDGE(i + 4); EDGE(i + 5); EDGE(i + 6); EDGE(i + 7);
  }
  for (; i + 4 <= ne; i += 4) {
    EDGE(i + 0); EDGE(i + 1); EDGE(i + 2); EDGE(i + 3);
  }
  for (; i < ne; ++i) EDGE(i);
#undef EDGE

  float r0 = fmaxf(acc.x + blo(sv) + bv.x, 0.f);
  float r1 = fmaxf(acc.y + bhi(sv) + bv.y, 0.f);
  hout[(size_t)node * 64 + ln] = (uint)f2b(r0) | ((uint)f2b(r1) << 16);
}

// ---------------- layer-2 gather (fp8 XW, HW cvt) + fused per-graph max pool --------
__global__ __launch_bounds__(256) void gather_fp8_pool(const uchar* __restrict__ XW8,
                                                       const uint* __restrict__ bins,
                                                       const int* __restrict__ cnt,
                                                       const float* __restrict__ bias,
                                                       ushort* __restrict__ partial2) {
  __shared__ ushort pm[4][128];
  int node = (blockIdx.x * 256 + threadIdx.x) >> 6;
  int w = threadIdx.x >> 6;
  int ln = threadIdx.x & 63;
  int ne = __builtin_amdgcn_readfirstlane(cnt[node]);
  if (ne > 64) ne = 64;
  ushort sv = *(const ushort*)(XW8 + (size_t)node * XW_LDB + 1024 + ln * 2);
  float2 bv = ((const float2*)bias)[ln];
  uint mv = bins[((size_t)node << 6) + ln];
  float2 acc = {0.f, 0.f};

#define EDGE(ii)                                                              \
  do {                                                                        \
    uint off = (uint)__builtin_amdgcn_readlane((int)mv, (ii));                \
    int wv_ = (int)*(const ushort*)(XW8 + (size_t)off * 2 + ln * 2);          \
    f32x2 f_ = fp8x2_to_f32(wv_);                                             \
    acc.x += f_.x; acc.y += f_.y;                                             \
  } while (0)
  int i = 0;
  for (; i + 8 <= ne; i += 8) {
    EDGE(i + 0); EDGE(i + 1); EDGE(i + 2); EDGE(i + 3);
    EDGE(i + 4); EDGE(i + 5); EDGE(i + 6); EDGE(i + 7);
  }
  for (; i + 4 <= ne; i += 4) {
    EDGE(i + 0); EDGE(i + 1); EDGE(i + 2); EDGE(i + 3);
  }
  for (; i < ne; ++i) EDGE(i);
#undef EDGE

  f32x2 sf = fp8x2_to_f32((int)sv);
  float r0 = fmaxf(acc.x + sf.x + bv.x, 0.f);
  float r1 = fmaxf(acc.y + sf.y + bv.y, 0.f);
  pm[w][ln * 2] = f2b(r0);
  pm[w][ln * 2 + 1] = f2b(r1);
  __syncthreads();
  int t = threadIdx.x;
  if (t < 128) {
    float m = fmaxf(fmaxf(b2f(pm[0][t]), b2f(pm[1][t])),
                    fmaxf(b2f(pm[2][t]), b2f(pm[3][t])));
    partial2[(size_t)blockIdx.x * 128 + t] = f2b(m);
  }
}

// ---------------- classifier: pooled = max over 256 block-partials; out = pooled@Wc+bc
__global__ __launch_bounds__(256) void classify2(const ushort* __restrict__ partial2,
                                                 const float* __restrict__ Wc,
                                                 const float* __restrict__ bc,
                                                 float* __restrict__ out) {
  __shared__ float red[2][128];
  __shared__ float pooled[128];
  int g = blockIdx.x, t = threadIdx.x;
  int d = t & 127, half = t >> 7;
  const ushort* base = partial2 + ((size_t)g * 256 + half * 128) * 128;
  float m = 0.f;
  for (int i = 0; i < 128; ++i) m = fmaxf(m, b2f(base[i * 128 + d]));
  red[half][d] = m;
  __syncthreads();
  if (t < 128) pooled[t] = fmaxf(red[0][t], red[1][t]);
  __syncthreads();
  if (t < 10) {
    float s = bc[t];
    for (int dd = 0; dd < DIM; ++dd) s += pooled[dd] * Wc[dd * 10 + t];
    out[g * 10 + t] = s;
  }
}

extern "C" void kernel_launch(void* const* d_in, const int* in_sizes, int n_in,
                              void* d_out, int out_size, void* d_ws, size_t ws_size,
                              hipStream_t stream) {
  const float* h       = (const float*)d_in[0];
  const float* W1      = (const float*)d_in[1];
  const float* W1_self = (const float*)d_in[2];
  const float* b1      = (const float*)d_in[3];
  const float* W2      = (const float*)d_in[4];
  const float* W2_self = (const float*)d_in[5];
  const float* b2      = (const float*)d_in[6];
  const float* Wc      = (const float*)d_in[7];
  const float* bc      = (const float*)d_in[8];
  const int* src   = (const int*)d_in[9];
  const int* dst   = (const int*)d_in[10];
  const int* etype = (const int*)d_in[11];
  float* out = (float*)d_out;

  char* ws = (char*)d_ws;
  ushort* XW      = (ushort*)(ws);           // layer-1 bf16 view
  uchar*  XW8     = (uchar*)(ws);            // layer-2 fp8 view (low 75MB)
  ushort* hb      = (ushort*)(ws + 150994944);
  ushort* h1b     = (ushort*)(ws + 167772160);
  ushort* Wt1c    = (ushort*)(ws + 184549376);
  ushort* Wt2c    = (ushort*)(ws + 184844288);
  int*    cnt     = (int*)(ws + 185139200);
  uint*   bins    = (uint*)(ws + 185401344);
  ushort* partial2= (ushort*)(ws + 202178560);

  const int g_gather = N_NODES / 4;          // 16384 (4 waves/block)

  // --- prep: conversion + weights + cnt zero in one kernel ---
  prep<<<8192 + 18 + 32, 256, 0, stream>>>(h, hb, W1, W1_self, W2, W2_self,
                                           Wt1c, Wt2c, cnt);

  // --- layer 1 (bf16 XW) GEMM + edge binning, 3:4 interleaved ---
  gemm1_fill<<<G_FUSED, 256, 0, stream>>>(hb, Wt1c, XW,
                                          src, dst, etype, cnt, bins);
  gather_bf16<<<g_gather, 256, 0, stream>>>((const uint*)XW, bins, cnt, b1,
                                            (uint*)h1b);

  // --- layer 2 (fp8 XW): pool fused into gather; h2 never materialized ---
  gemm_bk64_fp8<<<G_GEMM, 256, 0, stream>>>(h1b, Wt2c, XW8);
  gather_fp8_pool<<<g_gather, 256, 0, stream>>>(XW8, bins, cnt, b2, partial2);

  // --- classify ---
  classify2<<<N_GRAPHS, 256, 0, stream>>>(partial2, Wc, bc, out);

  (void)in_sizes; (void)n_in; (void)out_size; (void)ws_size;
}

// Round 20
// 197.718 us; speedup vs baseline: 1.0727x; 1.0727x over previous
//
#include <hip/hip_runtime.h>
#include <hip/hip_bf16.h>
#include <hip/hip_fp8.h>

// RGCN classifier, MI355X. Round 20: exact revert to round 18 (best measured:
// 207.6us, absmax 1.25). Round 19's HW-cvt + prep-fold changes were neutral-to-
// negative (gemm1_fill has a +-5-8% variance band; totals 207.6 vs 212.1).
// Structure: mixed-precision XW (layer-1 bf16 — quant error would amplify ~3-4x
// through layer-2's contraction; layer-2 fp8 e4m3 — error enters output only
// via pool+classifier). Round-12 packaging: fill 3:4-interleaved with gemm1.
// ws layout (bytes):
//   XW      @ 0          : 150,994,944  (layer1: bf16 [node][1152]; layer2: fp8 low 75MB)
//   hb      @ 150994944  : 16,777,216   (h bf16)
//   h1b     @ 167772160  : 16,777,216
//   Wt1c    @ 184549376  : 294,912      (bf16 [tile*128+n][k])
//   Wt2c    @ 184844288  : 294,912
//   cnt     @ 185139200  : 262,144      (int per node; doubles as degree)
//   bins    @ 185401344  : 16,777,216   (uint [node][64]: u32-off src*576+et*64)
//   partial2@ 202178560  : 4,194,304    (bf16 [16384][128] pool partials)

#define N_NODES 65536
#define N_EDGES 786432
#define DIM 128
#define NT 9
#define XW_LD (NT * DIM) /* 1152 elems (bf16 layer) */
#define XW_LDB 1152      /* bytes per row (fp8 layer) */
#define N_GRAPHS 64
#define G_GEMM 4608
#define G_FUSED 10752  /* per XCD: 1344 = 576 gemm + 768 fill, interleaved 3:4 */

typedef unsigned int uint;
typedef unsigned short ushort;
typedef unsigned char uchar;
typedef __attribute__((ext_vector_type(8))) short short8;
typedef __attribute__((ext_vector_type(4))) float f32x4;

__device__ inline ushort f2b(float f) {
  uint u = __float_as_uint(f);
  u += 0x7fff + ((u >> 16) & 1);   // RNE
  return (ushort)(u >> 16);
}
__device__ inline float b2f(ushort h) { return __uint_as_float(((uint)h) << 16); }
__device__ inline float blo(uint v) { return __uint_as_float(v << 16); }
__device__ inline float bhi(uint v) { return __uint_as_float(v & 0xffff0000u); }

__device__ inline uchar f2fp8(float f) {
  __hip_fp8_e4m3 q(f);
  return (uchar)q.__x;
}
__device__ inline float fp82f(uchar b) {
  __hip_fp8_e4m3 q;
  q.__x = b;
  return (float)q;
}

__device__ inline void gl_lds16(const void* g, void* l) {
  __builtin_amdgcn_global_load_lds(
      (const __attribute__((address_space(1))) unsigned int*)g,
      (__attribute__((address_space(3))) unsigned int*)l, 16, 0, 0);
}

// ---------------- prep: h conversion (8192 blocks) + weight transpose (18) ----------
__global__ __launch_bounds__(256) void prep(const float* __restrict__ h,
                                            ushort* __restrict__ hb,
                                            const float* __restrict__ W1,
                                            const float* __restrict__ W1s,
                                            const float* __restrict__ W2,
                                            const float* __restrict__ W2s,
                                            ushort* __restrict__ Wt1,
                                            ushort* __restrict__ Wt2) {
  const int bid = blockIdx.x, tid = threadIdx.x;
  if (bid < 8192) {
    int i = bid * 256 + tid;
    float4 v = ((const float4*)h)[i];
    ushort4 o;
    o.x = f2b(v.x); o.y = f2b(v.y); o.z = f2b(v.z); o.w = f2b(v.w);
    ((ushort4*)hb)[i] = o;
  } else {
    int b = bid - 8192;  // 0..17
    const float* S;
    ushort* D;
    int tile;
    if (b < 9) { D = Wt1; tile = b; S = (b < 8) ? (W1 + (size_t)b * 16384) : W1s; }
    else       { D = Wt2; tile = b - 9; S = (tile < 8) ? (W2 + (size_t)tile * 16384) : W2s; }
    for (int i = tid; i < 16384; i += 256) {
      int n = i >> 7, k = i & 127;
      D[((size_t)tile * 128 + n) * 128 + k] = f2b(S[k * 128 + n]);
    }
  }
}

// ---------------- GEMM K-loop core (shared): acc = A_tile @ W_tile ----------------
__device__ __forceinline__ void gemm_core(const char* Ag, const char* Bg,
                                          char* lds, f32x4 (*acc)[4]) {
  const int tid = threadIdx.x, wv = tid >> 6, ln = tid & 63;
  const int wm = wv >> 1, wn = wv & 1, lr = ln & 15, kq = ln >> 4;
#pragma unroll
  for (int kt = 0; kt < 2; ++kt) {
    if (kt) __syncthreads();                  // prior phase's reads done
#pragma unroll
    for (int it = 0; it < 4; ++it) {
      int chunk = it * 4096 + wv * 1024;      // wave-uniform LDS base, 16KB total
      int p = chunk + ln * 16;                // linear lds byte pos
      int row = p >> 7, inb = p & 127;        // 128B rows
      int sw = inb ^ ((row & 7) << 4);        // pre-swizzled global source
      size_t gb = (size_t)row * 256 + (size_t)kt * 128 + sw;
      gl_lds16(Ag + gb, lds + chunk);
      gl_lds16(Bg + gb, lds + 16384 + chunk);
    }
    asm volatile("s_waitcnt vmcnt(0)" ::: "memory");
    __syncthreads();
#pragma unroll
    for (int k2 = 0; k2 < 2; ++k2) {
      const int kb = k2 * 64 + kq * 16;
      short8 a[4], b[4];
#pragma unroll
      for (int m = 0; m < 4; ++m) {
        int row = wm * 64 + m * 16 + lr;
        a[m] = *(const short8*)(lds + ((row * 128 + kb) ^ ((row & 7) << 4)));
      }
#pragma unroll
      for (int n = 0; n < 4; ++n) {
        int col = wn * 64 + n * 16 + lr;
        b[n] = *(const short8*)(lds + 16384 + ((col * 128 + kb) ^ ((col & 7) << 4)));
      }
#pragma unroll
      for (int m = 0; m < 4; ++m)
#pragma unroll
        for (int n = 0; n < 4; ++n)
          acc[m][n] = __builtin_amdgcn_mfma_f32_16x16x32_bf16(a[m], b[n], acc[m][n], 0, 0, 0);
    }
  }
}

// ---------------- layer-1 GEMM body: bf16 C, ldc=1152 elems ----------------
__device__ __forceinline__ void gemm_body_bf16(const ushort* __restrict__ A,
                                               const ushort* __restrict__ Bt,
                                               ushort* __restrict__ C,
                                               int tile, char* lds) {
  const int bm = tile / 9, bn = tile % 9;
  const int tid = threadIdx.x, wv = tid >> 6, ln = tid & 63;
  const int wm = wv >> 1, wn = wv & 1, lr = ln & 15, kq = ln >> 4;
  f32x4 acc[4][4];
#pragma unroll
  for (int m = 0; m < 4; ++m)
#pragma unroll
    for (int n = 0; n < 4; ++n) acc[m][n] = (f32x4){0.f, 0.f, 0.f, 0.f};
  gemm_core((const char*)(A + (size_t)bm * 128 * 128),
            (const char*)(Bt + (size_t)bn * 128 * 128), lds, acc);

  __syncthreads();  // stage-buffer reads complete before reuse
#pragma unroll
  for (int m = 0; m < 4; ++m) {
    int rb0 = wm * 64 + m * 16 + kq * 4;
#pragma unroll
    for (int n = 0; n < 4; ++n) {
      int col = wn * 64 + n * 16 + lr;
#pragma unroll
      for (int e = 0; e < 4; ++e) {
        int row = rb0 + e;
        int off = (row * 256 + col * 2) ^ ((row & 7) << 4);
        *(ushort*)(lds + off) = f2b(acc[m][n][e]);
      }
    }
  }
  __syncthreads();
  char* Cg = (char*)C + (size_t)(bm * 128) * XW_LD * 2 + (size_t)bn * 256;
#pragma unroll
  for (int it = 0; it < 8; ++it) {
    int p = it * 4096 + tid * 16;
    int row = p >> 8, inb = p & 255;
    short8 v = *(const short8*)(lds + row * 256 + (inb ^ ((row & 7) << 4)));
    *(short8*)(Cg + (size_t)row * XW_LD * 2 + inb) = v;
  }
}

// ---------------- layer-2 GEMM: fp8 C, row stride 1152 bytes ----------------
__global__ __launch_bounds__(256, 4) void gemm_bk64_fp8(const ushort* __restrict__ A,
                                                        const ushort* __restrict__ Bt,
                                                        uchar* __restrict__ C) {
  __shared__ char lds[32768];
  const int tile = (blockIdx.x & 7) * 576 + (blockIdx.x >> 3);
  const int bm = tile / 9, bn = tile % 9;
  const int tid = threadIdx.x, wv = tid >> 6, ln = tid & 63;
  const int wm = wv >> 1, wn = wv & 1, lr = ln & 15, kq = ln >> 4;
  f32x4 acc[4][4];
#pragma unroll
  for (int m = 0; m < 4; ++m)
#pragma unroll
    for (int n = 0; n < 4; ++n) acc[m][n] = (f32x4){0.f, 0.f, 0.f, 0.f};
  gemm_core((const char*)(A + (size_t)bm * 128 * 128),
            (const char*)(Bt + (size_t)bn * 128 * 128), lds, acc);

  __syncthreads();
#pragma unroll
  for (int m = 0; m < 4; ++m) {
    int rb0 = wm * 64 + m * 16 + kq * 4;
#pragma unroll
    for (int n = 0; n < 4; ++n) {
      int col = wn * 64 + n * 16 + lr;
#pragma unroll
      for (int e = 0; e < 4; ++e) {
        int row = rb0 + e;
        int off = (row * 128 + col) ^ ((row & 7) << 4);
        *(uchar*)(lds + off) = f2fp8(acc[m][n][e]);
      }
    }
  }
  __syncthreads();
  uchar* Cg = C + (size_t)(bm * 128) * XW_LDB + (size_t)bn * 128;
#pragma unroll
  for (int it = 0; it < 4; ++it) {
    int p = it * 4096 + tid * 16;
    int row = p >> 7, inb = p & 127;
    short8 v = *(const short8*)(lds + row * 128 + (inb ^ ((row & 7) << 4)));
    *(short8*)(Cg + (size_t)row * XW_LDB + inb) = v;
  }
}

// layer-1 GEMM + interleaved edge binning (round-12 packaging, best measured).
// Per XCD (bid&7) the sequence s=bid>>3 splits 3 gemm : 4 fill per group of 7.
// fill: slice=xcd owns dst [xcd*8192,(xcd+1)*8192); rec = src*576 + et*64
// (u32-offset of the bf16 XW row; fp8 byte-offset = rec*2).
__global__ __launch_bounds__(256, 4) void gemm1_fill(const ushort* __restrict__ A,
                                                     const ushort* __restrict__ Bt,
                                                     ushort* __restrict__ C,
                                                     const int* __restrict__ src,
                                                     const int* __restrict__ dst,
                                                     const int* __restrict__ et,
                                                     int* __restrict__ cnt,
                                                     uint* __restrict__ bins) {
  __shared__ char lds[32768];
  const int bid = blockIdx.x;            // 10752
  const int xcd = bid & 7, s = bid >> 3; // s in [0,1344)
  const int q = s / 7, r = s % 7;
  if (r < 3) {
    gemm_body_bf16(A, Bt, C, xcd * 576 + q * 3 + r, lds);
    return;
  }
  const int f = q * 4 + (r - 3);         // 0..767
  const int e0 = f * 1024 + threadIdx.x * 4;
  int4 d4 = *(const int4*)(dst + e0);
  int4 s4 = *(const int4*)(src + e0);
  int4 t4 = *(const int4*)(et + e0);
  uint r0 = (uint)s4.x * 576u + (uint)t4.x * 64u;
  uint r1 = (uint)s4.y * 576u + (uint)t4.y * 64u;
  uint r2 = (uint)s4.z * 576u + (uint)t4.z * 64u;
  uint r3 = (uint)s4.w * 576u + (uint)t4.w * 64u;
  if ((d4.x >> 13) == xcd) {
    int rk = atomicAdd(&cnt[d4.x], 1);
    if (rk < 64) bins[((size_t)d4.x << 6) + rk] = r0;
  }
  if ((d4.y >> 13) == xcd) {
    int rk = atomicAdd(&cnt[d4.y], 1);
    if (rk < 64) bins[((size_t)d4.y << 6) + rk] = r1;
  }
  if ((d4.z >> 13) == xcd) {
    int rk = atomicAdd(&cnt[d4.z], 1);
    if (rk < 64) bins[((size_t)d4.z << 6) + rk] = r2;
  }
  if ((d4.w >> 13) == xcd) {
    int rk = atomicAdd(&cnt[d4.w], 1);
    if (rk < 64) bins[((size_t)d4.w << 6) + rk] = r3;
  }
}

// ---------------- layer-1 gather (bf16 XW): h1 = relu(sum + self + b1) --------------
// Wave per node (4 nodes/block); bin preload + readlane; 8/4-deep loads.
__global__ __launch_bounds__(256) void gather_bf16(const uint* __restrict__ XWu,
                                                   const uint* __restrict__ bins,
                                                   const int* __restrict__ cnt,
                                                   const float* __restrict__ bias,
                                                   uint* __restrict__ hout) {
  int node = (blockIdx.x * 256 + threadIdx.x) >> 6;
  int ln = threadIdx.x & 63;
  int ne = __builtin_amdgcn_readfirstlane(cnt[node]);
  if (ne > 64) ne = 64;
  uint sv = XWu[(size_t)node * 576 + 512 + ln];
  float2 bv = ((const float2*)bias)[ln];
  uint mv = bins[((size_t)node << 6) + ln];
  float2 acc = {0.f, 0.f};

#define EDGE(ii)                                                              \
  do {                                                                        \
    uint off = (uint)__builtin_amdgcn_readlane((int)mv, (ii));                \
    uint v_ = XWu[off + ln];                                                  \
    acc.x += blo(v_); acc.y += bhi(v_);                                       \
  } while (0)
  int i = 0;
  for (; i + 8 <= ne; i += 8) {
    EDGE(i + 0); EDGE(i + 1); EDGE(i + 2); EDGE(i + 3);
    EDGE(i + 4); EDGE(i + 5); EDGE(i + 6); EDGE(i + 7);
  }
  for (; i + 4 <= ne; i += 4) {
    EDGE(i + 0); EDGE(i + 1); EDGE(i + 2); EDGE(i + 3);
  }
  for (; i < ne; ++i) EDGE(i);
#undef EDGE

  float r0 = fmaxf(acc.x + blo(sv) + bv.x, 0.f);
  float r1 = fmaxf(acc.y + bhi(sv) + bv.y, 0.f);
  hout[(size_t)node * 64 + ln] = (uint)f2b(r0) | ((uint)f2b(r1) << 16);
}

// ---------------- layer-2 gather (fp8 XW) + fused per-graph max pool ----------------
// fp8 byte-offset of a row = rec*2 (rec is the bf16 u32-offset). 2 bytes/lane.
__global__ __launch_bounds__(256) void gather_fp8_pool(const uchar* __restrict__ XW8,
                                                       const uint* __restrict__ bins,
                                                       const int* __restrict__ cnt,
                                                       const float* __restrict__ bias,
                                                       ushort* __restrict__ partial2) {
  __shared__ ushort pm[4][128];
  int node = (blockIdx.x * 256 + threadIdx.x) >> 6;
  int w = threadIdx.x >> 6;
  int ln = threadIdx.x & 63;
  int ne = __builtin_amdgcn_readfirstlane(cnt[node]);
  if (ne > 64) ne = 64;
  ushort sv = *(const ushort*)(XW8 + (size_t)node * XW_LDB + 1024 + ln * 2);
  float2 bv = ((const float2*)bias)[ln];
  uint mv = bins[((size_t)node << 6) + ln];
  float2 acc = {0.f, 0.f};

#define EDGE(ii)                                                              \
  do {                                                                        \
    uint off = (uint)__builtin_amdgcn_readlane((int)mv, (ii));                \
    ushort wv_ = *(const ushort*)(XW8 + (size_t)off * 2 + ln * 2);            \
    acc.x += fp82f((uchar)(wv_ & 0xff));                                      \
    acc.y += fp82f((uchar)(wv_ >> 8));                                        \
  } while (0)
  int i = 0;
  for (; i + 8 <= ne; i += 8) {
    EDGE(i + 0); EDGE(i + 1); EDGE(i + 2); EDGE(i + 3);
    EDGE(i + 4); EDGE(i + 5); EDGE(i + 6); EDGE(i + 7);
  }
  for (; i + 4 <= ne; i += 4) {
    EDGE(i + 0); EDGE(i + 1); EDGE(i + 2); EDGE(i + 3);
  }
  for (; i < ne; ++i) EDGE(i);
#undef EDGE

  float r0 = fmaxf(acc.x + fp82f((uchar)(sv & 0xff)) + bv.x, 0.f);
  float r1 = fmaxf(acc.y + fp82f((uchar)(sv >> 8)) + bv.y, 0.f);
  pm[w][ln * 2] = f2b(r0);
  pm[w][ln * 2 + 1] = f2b(r1);
  __syncthreads();
  int t = threadIdx.x;
  if (t < 128) {
    float m = fmaxf(fmaxf(b2f(pm[0][t]), b2f(pm[1][t])),
                    fmaxf(b2f(pm[2][t]), b2f(pm[3][t])));
    partial2[(size_t)blockIdx.x * 128 + t] = f2b(m);
  }
}

// ---------------- classifier: pooled = max over 256 block-partials; out = pooled@Wc+bc
__global__ __launch_bounds__(256) void classify2(const ushort* __restrict__ partial2,
                                                 const float* __restrict__ Wc,
                                                 const float* __restrict__ bc,
                                                 float* __restrict__ out) {
  __shared__ float red[2][128];
  __shared__ float pooled[128];
  int g = blockIdx.x, t = threadIdx.x;
  int d = t & 127, half = t >> 7;
  const ushort* base = partial2 + ((size_t)g * 256 + half * 128) * 128;
  float m = 0.f;
  for (int i = 0; i < 128; ++i) m = fmaxf(m, b2f(base[i * 128 + d]));
  red[half][d] = m;
  __syncthreads();
  if (t < 128) pooled[t] = fmaxf(red[0][t], red[1][t]);
  __syncthreads();
  if (t < 10) {
    float s = bc[t];
    for (int dd = 0; dd < DIM; ++dd) s += pooled[dd] * Wc[dd * 10 + t];
    out[g * 10 + t] = s;
  }
}

extern "C" void kernel_launch(void* const* d_in, const int* in_sizes, int n_in,
                              void* d_out, int out_size, void* d_ws, size_t ws_size,
                              hipStream_t stream) {
  const float* h       = (const float*)d_in[0];
  const float* W1      = (const float*)d_in[1];
  const float* W1_self = (const float*)d_in[2];
  const float* b1      = (const float*)d_in[3];
  const float* W2      = (const float*)d_in[4];
  const float* W2_self = (const float*)d_in[5];
  const float* b2      = (const float*)d_in[6];
  const float* Wc      = (const float*)d_in[7];
  const float* bc      = (const float*)d_in[8];
  const int* src   = (const int*)d_in[9];
  const int* dst   = (const int*)d_in[10];
  const int* etype = (const int*)d_in[11];
  float* out = (float*)d_out;

  char* ws = (char*)d_ws;
  ushort* XW      = (ushort*)(ws);           // layer-1 bf16 view
  uchar*  XW8     = (uchar*)(ws);            // layer-2 fp8 view (low 75MB)
  ushort* hb      = (ushort*)(ws + 150994944);
  ushort* h1b     = (ushort*)(ws + 167772160);
  ushort* Wt1c    = (ushort*)(ws + 184549376);
  ushort* Wt2c    = (ushort*)(ws + 184844288);
  int*    cnt     = (int*)(ws + 185139200);
  uint*   bins    = (uint*)(ws + 185401344);
  ushort* partial2= (ushort*)(ws + 202178560);

  const int g_gather = N_NODES / 4;          // 16384 (4 waves/block)

  // --- prep: conversion + weights in one kernel ---
  hipMemsetAsync(cnt, 0, N_NODES * sizeof(int), stream);
  prep<<<8192 + 18, 256, 0, stream>>>(h, hb, W1, W1_self, W2, W2_self, Wt1c, Wt2c);

  // --- layer 1 (bf16 XW) GEMM + edge binning, 3:4 interleaved ---
  gemm1_fill<<<G_FUSED, 256, 0, stream>>>(hb, Wt1c, XW,
                                          src, dst, etype, cnt, bins);
  gather_bf16<<<g_gather, 256, 0, stream>>>((const uint*)XW, bins, cnt, b1,
                                            (uint*)h1b);

  // --- layer 2 (fp8 XW): pool fused into gather; h2 never materialized ---
  gemm_bk64_fp8<<<G_GEMM, 256, 0, stream>>>(h1b, Wt2c, XW8);
  gather_fp8_pool<<<g_gather, 256, 0, stream>>>(XW8, bins, cnt, b2, partial2);

  // --- classify ---
  classify2<<<N_GRAPHS, 256, 0, stream>>>(partial2, Wc, bc, out);

  (void)in_sizes; (void)n_in; (void)out_size; (void)ws_size;
}